// Round 1
// baseline (1675.328 us; speedup 1.0000x reference)
//
#include <hip/hip_runtime.h>

typedef short short8 __attribute__((ext_vector_type(8)));
typedef float f32x4 __attribute__((ext_vector_type(4)));
typedef unsigned short u16;
typedef unsigned int u32;

__device__ __forceinline__ u16 f2bf(float f) {
    union { float f; u32 u; } v; v.f = f;
    u32 r = (v.u + 0x7FFFu + ((v.u >> 16) & 1u)) >> 16;
    return (u16)r;
}

// One MLP layer: X (bf16 in LDS, [64][K+8]) @ Wt (bf16 global, [N][K]) + bias,
// row-wise LayerNorm across N, optional SiLU.
// !FINAL: writes bf16 to Ol [64][N+8].  FINAL: writes f32 to Fl [64][N+4].
// Block = 256 threads = 4 waves; wave w owns cols [w*N/4, (w+1)*N/4).
template<int K, int N, bool SILU, bool FINAL>
__device__ __forceinline__ void mlp_layer(
    const u16* Xl, u16* Ol, float* Fl,
    float* red, float* stats,
    const u16* __restrict__ Wt, const float* __restrict__ bias,
    const float* __restrict__ gamma, const float* __restrict__ beta)
{
    constexpr int LDX = K + 8;
    constexpr int LDO = N + 8;
    constexpr int LDF = N + 4;
    constexpr int NT = N / 64;   // 16-col tiles per wave
    const int tid = threadIdx.x;
    const int wave = tid >> 6;
    const int lane = tid & 63;
    const int l15 = lane & 15;
    const int lg = lane >> 4;
    const int nbase = wave * (N / 4);

    f32x4 acc[4][NT];
    #pragma unroll
    for (int mt = 0; mt < 4; ++mt)
        #pragma unroll
        for (int nt = 0; nt < NT; ++nt)
            acc[mt][nt] = (f32x4){0.f, 0.f, 0.f, 0.f};

    for (int ks = 0; ks < K / 32; ++ks) {
        short8 a[4];
        #pragma unroll
        for (int mt = 0; mt < 4; ++mt)
            a[mt] = *(const short8*)(Xl + (mt * 16 + l15) * LDX + ks * 32 + lg * 8);
        #pragma unroll
        for (int nt = 0; nt < NT; ++nt) {
            short8 b = *(const short8*)(Wt + (size_t)(nbase + nt * 16 + l15) * K + ks * 32 + lg * 8);
            #pragma unroll
            for (int mt = 0; mt < 4; ++mt)
                acc[mt][nt] = __builtin_amdgcn_mfma_f32_16x16x32_bf16(a[mt], b, acc[mt][nt], 0, 0, 0);
        }
    }

    // bias + per-n affine params for this lane's columns
    float bv[NT], gv[NT], btv[NT];
    #pragma unroll
    for (int nt = 0; nt < NT; ++nt) {
        int n = nbase + nt * 16 + l15;
        bv[nt] = bias[n]; gv[nt] = gamma[n]; btv[nt] = beta[n];
    }
    #pragma unroll
    for (int mt = 0; mt < 4; ++mt)
        #pragma unroll
        for (int nt = 0; nt < NT; ++nt)
            #pragma unroll
            for (int r = 0; r < 4; ++r)
                acc[mt][nt][r] += bv[nt];

    // per-row partial sum / sumsq over this wave's N/4 columns.
    // C/D layout: col = l15 (varies across the 16-lane group), row = lg*4+r.
    #pragma unroll
    for (int mt = 0; mt < 4; ++mt) {
        float s[4] = {0.f, 0.f, 0.f, 0.f}, q[4] = {0.f, 0.f, 0.f, 0.f};
        #pragma unroll
        for (int nt = 0; nt < NT; ++nt)
            #pragma unroll
            for (int r = 0; r < 4; ++r) {
                float v = acc[mt][nt][r];
                s[r] += v; q[r] += v * v;
            }
        #pragma unroll
        for (int o = 1; o < 16; o <<= 1) {
            #pragma unroll
            for (int r = 0; r < 4; ++r) {
                s[r] += __shfl_xor(s[r], o, 64);
                q[r] += __shfl_xor(q[r], o, 64);
            }
        }
        if (l15 == 0) {
            int row = mt * 16 + lg * 4;
            #pragma unroll
            for (int r = 0; r < 4; ++r) {
                red[(wave * 64 + row + r) * 2 + 0] = s[r];
                red[(wave * 64 + row + r) * 2 + 1] = q[r];
            }
        }
    }
    __syncthreads();
    if (tid < 64) {
        float s = 0.f, q = 0.f;
        #pragma unroll
        for (int w = 0; w < 4; ++w) {
            s += red[(w * 64 + tid) * 2 + 0];
            q += red[(w * 64 + tid) * 2 + 1];
        }
        float mean = s / (float)N;
        float var = q / (float)N - mean * mean;
        stats[tid * 2 + 0] = mean;
        stats[tid * 2 + 1] = rsqrtf(var + 1e-5f);
    }
    __syncthreads();   // also guarantees all X reads done -> Ol/Fl may alias Xl

    #pragma unroll
    for (int mt = 0; mt < 4; ++mt)
        #pragma unroll
        for (int r = 0; r < 4; ++r) {
            int row = mt * 16 + lg * 4 + r;
            float mean = stats[row * 2 + 0];
            float rstd = stats[row * 2 + 1];
            #pragma unroll
            for (int nt = 0; nt < NT; ++nt) {
                float h = (acc[mt][nt][r] - mean) * rstd * gv[nt] + btv[nt];
                if (SILU) h = h / (1.f + __expf(-h));
                int col = nbase + nt * 16 + l15;
                if (FINAL) Fl[row * LDF + col] = h;
                else       Ol[row * LDO + col] = f2bf(h);
            }
        }
    __syncthreads();
}

// ---------------- edge kernel: gather+concat -> MLP(384->384->128) -> residual + scatter
__global__ __launch_bounds__(256) void edge_kernel(
    const float* __restrict__ e_h, const float* __restrict__ h_src, const float* __restrict__ h_dst,
    const int* __restrict__ src_idx, const int* __restrict__ dst_idx,
    const u16* __restrict__ ew0t, const float* __restrict__ eb0, const float* __restrict__ eg0, const float* __restrict__ ebt0,
    const u16* __restrict__ ew1t, const float* __restrict__ eb1, const float* __restrict__ eg1, const float* __restrict__ ebt1,
    float* __restrict__ m_sum, u32* __restrict__ deg,
    float* __restrict__ e_out, int E)
{
    __shared__ alignas(16) u16 Xbuf[64 * 392];   // 50176 B; reused for H1 (bf16) and F (f32 [64][132])
    __shared__ float red[4 * 64 * 2];
    __shared__ float stats[64 * 2];
    const int tid = threadIdx.x;
    const int eBase = blockIdx.x * 64;

    if (tid < 64) {
        int e = eBase + tid;
        if (e < E) atomicAdd(&deg[dst_idx[e]], 1u);
    }
    // stage X = [e_h | h_src[s] | h_dst[d]] as bf16
    for (int i = tid; i < 64 * 96; i += 256) {
        int row = i / 96;
        int col = (i % 96) * 4;
        int e = eBase + row;
        float4 v = make_float4(0.f, 0.f, 0.f, 0.f);
        if (e < E) {
            const float* p;
            if (col < 128)      p = e_h   + (size_t)e * 128 + col;
            else if (col < 256) p = h_src + (size_t)src_idx[e] * 128 + (col - 128);
            else                p = h_dst + (size_t)dst_idx[e] * 128 + (col - 256);
            v = *(const float4*)p;
        }
        ushort4 u;
        u.x = f2bf(v.x); u.y = f2bf(v.y); u.z = f2bf(v.z); u.w = f2bf(v.w);
        *(ushort4*)(Xbuf + row * 392 + col) = u;
    }
    __syncthreads();

    mlp_layer<384, 384, true,  false>(Xbuf, Xbuf, nullptr, red, stats, ew0t, eb0, eg0, ebt0);
    mlp_layer<384, 128, false, true >(Xbuf, nullptr, (float*)Xbuf, red, stats, ew1t, eb1, eg1, ebt1);

    const float* F = (const float*)Xbuf;
    for (int i = tid; i < 64 * 128; i += 256) {
        int row = i >> 7, col = i & 127;
        int e = eBase + row;
        if (e < E) {
            float v = F[row * 132 + col];
            e_out[(size_t)e * 128 + col] = e_h[(size_t)e * 128 + col] + v;
            atomicAdd(&m_sum[(size_t)dst_idx[e] * 128 + col], v);
        }
    }
}

// ---------------- dst kernel: [h_dst | m_sum] -> MLP(256->256->128), deg mask, residual
__global__ __launch_bounds__(256) void dst_kernel(
    const float* __restrict__ h_dst, const float* __restrict__ m_sum, const u32* __restrict__ deg,
    const u16* __restrict__ dw0t, const float* __restrict__ db0, const float* __restrict__ dg0, const float* __restrict__ dbt0,
    const u16* __restrict__ dw1t, const float* __restrict__ db1, const float* __restrict__ dg1, const float* __restrict__ dbt1,
    float* __restrict__ hd_out, int ND)
{
    __shared__ alignas(16) u16 Xbuf[64 * 264];   // 33792 B; F (f32 [64][132]) aliases exactly
    __shared__ float red[4 * 64 * 2];
    __shared__ float stats[64 * 2];
    const int tid = threadIdx.x;
    const int nBase = blockIdx.x * 64;

    for (int i = tid; i < 64 * 64; i += 256) {
        int row = i / 64;
        int col = (i % 64) * 4;
        int n = nBase + row;
        float4 v = make_float4(0.f, 0.f, 0.f, 0.f);
        if (n < ND) {
            const float* p = (col < 128) ? (h_dst + (size_t)n * 128 + col)
                                         : (m_sum + (size_t)n * 128 + (col - 128));
            v = *(const float4*)p;
        }
        ushort4 u;
        u.x = f2bf(v.x); u.y = f2bf(v.y); u.z = f2bf(v.z); u.w = f2bf(v.w);
        *(ushort4*)(Xbuf + row * 264 + col) = u;
    }
    __syncthreads();

    mlp_layer<256, 256, true,  false>(Xbuf, Xbuf, nullptr, red, stats, dw0t, db0, dg0, dbt0);
    mlp_layer<256, 128, false, true >(Xbuf, nullptr, (float*)Xbuf, red, stats, dw1t, db1, dg1, dbt1);

    const float* F = (const float*)Xbuf;
    for (int i = tid; i < 64 * 128; i += 256) {
        int row = i >> 7, col = i & 127;
        int n = nBase + row;
        if (n < ND) {
            float hn = (deg[n] > 0u) ? F[row * 132 + col] : 0.f;
            hd_out[(size_t)n * 128 + col] = h_dst[(size_t)n * 128 + col] + hn;
        }
    }
}

// ---------------- src kernel: h_src -> MLP(128->128->128), residual
__global__ __launch_bounds__(256) void src_kernel(
    const float* __restrict__ h_src,
    const u16* __restrict__ sw0t, const float* __restrict__ sb0, const float* __restrict__ sg0, const float* __restrict__ sbt0,
    const u16* __restrict__ sw1t, const float* __restrict__ sb1, const float* __restrict__ sg1, const float* __restrict__ sbt1,
    float* __restrict__ hs_out, int NS)
{
    __shared__ alignas(16) u16 Xbuf[64 * 264];   // sized for F (f32 [64][132]); layer1 uses [64][136]
    __shared__ float red[4 * 64 * 2];
    __shared__ float stats[64 * 2];
    const int tid = threadIdx.x;
    const int nBase = blockIdx.x * 64;

    for (int i = tid; i < 64 * 32; i += 256) {
        int row = i / 32;
        int col = (i % 32) * 4;
        int n = nBase + row;
        float4 v = make_float4(0.f, 0.f, 0.f, 0.f);
        if (n < NS) v = *(const float4*)(h_src + (size_t)n * 128 + col);
        ushort4 u;
        u.x = f2bf(v.x); u.y = f2bf(v.y); u.z = f2bf(v.z); u.w = f2bf(v.w);
        *(ushort4*)(Xbuf + row * 136 + col) = u;
    }
    __syncthreads();

    mlp_layer<128, 128, true,  false>(Xbuf, Xbuf, nullptr, red, stats, sw0t, sb0, sg0, sbt0);
    mlp_layer<128, 128, false, true >(Xbuf, nullptr, (float*)Xbuf, red, stats, sw1t, sb1, sg1, sbt1);

    const float* F = (const float*)Xbuf;
    for (int i = tid; i < 64 * 128; i += 256) {
        int row = i >> 7, col = i & 127;
        int n = nBase + row;
        if (n < NS)
            hs_out[(size_t)n * 128 + col] = h_src[(size_t)n * 128 + col] + F[row * 132 + col];
    }
}

// ---------------- weight transpose+cast: W[k][n] f32 -> Wt[n][k] bf16
__global__ __launch_bounds__(256) void wtrans(const float* __restrict__ W, u16* __restrict__ Wt, int K, int N) {
    int i = blockIdx.x * 256 + threadIdx.x;
    if (i < K * N) {
        int k = i / N, n = i % N;
        Wt[(size_t)n * K + k] = f2bf(W[i]);
    }
}

extern "C" void kernel_launch(void* const* d_in, const int* in_sizes, int n_in,
                              void* d_out, int out_size, void* d_ws, size_t ws_size,
                              hipStream_t stream) {
    const float* e_h   = (const float*)d_in[0];
    const float* h_src = (const float*)d_in[1];
    const float* h_dst = (const float*)d_in[2];
    const int* src_idx = (const int*)d_in[3];
    const int* dst_idx = (const int*)d_in[4];
    const float* ew0 = (const float*)d_in[5];
    const float* eb0 = (const float*)d_in[6];
    const float* eg0 = (const float*)d_in[7];
    const float* ebt0 = (const float*)d_in[8];
    const float* ew1 = (const float*)d_in[9];
    const float* eb1 = (const float*)d_in[10];
    const float* eg1 = (const float*)d_in[11];
    const float* ebt1 = (const float*)d_in[12];
    const float* dw0 = (const float*)d_in[13];
    const float* db0 = (const float*)d_in[14];
    const float* dg0 = (const float*)d_in[15];
    const float* dbt0 = (const float*)d_in[16];
    const float* dw1 = (const float*)d_in[17];
    const float* db1 = (const float*)d_in[18];
    const float* dg1 = (const float*)d_in[19];
    const float* dbt1 = (const float*)d_in[20];
    const float* sw0 = (const float*)d_in[21];
    const float* sb0 = (const float*)d_in[22];
    const float* sg0 = (const float*)d_in[23];
    const float* sbt0 = (const float*)d_in[24];
    const float* sw1 = (const float*)d_in[25];
    const float* sb1 = (const float*)d_in[26];
    const float* sg1 = (const float*)d_in[27];
    const float* sbt1 = (const float*)d_in[28];

    const int E  = in_sizes[0] / 128;
    const int NS = in_sizes[1] / 128;
    const int ND = in_sizes[2] / 128;

    // workspace carve-up
    char* ws = (char*)d_ws;
    float* m_sum = (float*)ws;                                   // ND*128 f32
    u32* deg = (u32*)(ws + (size_t)ND * 128 * 4);                // ND u32
    u16* ew0t = (u16*)(ws + (size_t)ND * 128 * 4 + (size_t)ND * 4);
    u16* ew1t = ew0t + 384 * 384;
    u16* dw0t = ew1t + 128 * 384;
    u16* dw1t = dw0t + 256 * 256;
    u16* sw0t = dw1t + 128 * 256;
    u16* sw1t = sw0t + 128 * 128;

    hipMemsetAsync(m_sum, 0, (size_t)ND * 128 * 4 + (size_t)ND * 4, stream);

    wtrans<<<(384 * 384 + 255) / 256, 256, 0, stream>>>(ew0, ew0t, 384, 384);
    wtrans<<<(384 * 128 + 255) / 256, 256, 0, stream>>>(ew1, ew1t, 384, 128);
    wtrans<<<(256 * 256 + 255) / 256, 256, 0, stream>>>(dw0, dw0t, 256, 256);
    wtrans<<<(256 * 128 + 255) / 256, 256, 0, stream>>>(dw1, dw1t, 256, 128);
    wtrans<<<(128 * 128 + 255) / 256, 256, 0, stream>>>(sw0, sw0t, 128, 128);
    wtrans<<<(128 * 128 + 255) / 256, 256, 0, stream>>>(sw1, sw1t, 128, 128);

    float* e_out  = (float*)d_out;
    float* hs_out = e_out + (size_t)E * 128;
    float* hd_out = hs_out + (size_t)NS * 128;

    edge_kernel<<<(E + 63) / 64, 256, 0, stream>>>(
        e_h, h_src, h_dst, src_idx, dst_idx,
        ew0t, eb0, eg0, ebt0, ew1t, eb1, eg1, ebt1,
        m_sum, deg, e_out, E);

    src_kernel<<<(NS + 63) / 64, 256, 0, stream>>>(
        h_src, sw0t, sb0, sg0, sbt0, sw1t, sb1, sg1, sbt1, hs_out, NS);

    dst_kernel<<<(ND + 63) / 64, 256, 0, stream>>>(
        h_dst, m_sum, deg,
        dw0t, db0, dg0, dbt0, dw1t, db1, dg1, dbt1,
        hd_out, ND);
}

// Round 2
// 1271.039 us; speedup vs baseline: 1.3181x; 1.3181x over previous
//
#include <hip/hip_runtime.h>

typedef short short8 __attribute__((ext_vector_type(8)));
typedef float f32x4 __attribute__((ext_vector_type(4)));
typedef unsigned short u16;
typedef unsigned int u32;

__device__ __forceinline__ u16 f2bf(float f) {
    union { float f; u32 u; } v; v.f = f;
    u32 r = (v.u + 0x7FFFu + ((v.u >> 16) & 1u)) >> 16;
    return (u16)r;
}
__device__ __forceinline__ float bf2f(u16 b) {
    union { u32 u; float f; } v; v.u = ((u32)b) << 16; return v.f;
}

// One MLP layer: X (bf16 in LDS, [64][K+8]) @ Wt (bf16 global, [N][K]) + bias,
// row-wise LayerNorm across N, optional SiLU.
// !FINAL: writes bf16 to Ol [64][N+8].  FINAL: writes f32 to Fl [64][N+4].
// Block = 256 threads = 4 waves; wave w owns cols [w*N/4, (w+1)*N/4).
// B loads are double-buffered (b0/b1) so L2 latency hides under the MFMAs.
template<int K, int N, bool SILU, bool FINAL>
__device__ __forceinline__ void mlp_layer(
    const u16* Xl, u16* Ol, float* Fl,
    float* red, float* stats,
    const u16* __restrict__ Wt, const float* __restrict__ bias,
    const float* __restrict__ gamma, const float* __restrict__ beta)
{
    constexpr int LDX = K + 8;
    constexpr int LDO = N + 8;
    constexpr int LDF = N + 4;
    constexpr int NT = N / 64;   // 16-col tiles per wave
    constexpr int KS = K / 32;
    static_assert((KS & 1) == 0, "KS must be even");
    const int tid = threadIdx.x;
    const int wave = tid >> 6;
    const int lane = tid & 63;
    const int l15 = lane & 15;
    const int lg = lane >> 4;
    const int nbase = wave * (N / 4);

    const u16* wp[NT];
    #pragma unroll
    for (int nt = 0; nt < NT; ++nt)
        wp[nt] = Wt + (size_t)(nbase + nt * 16 + l15) * K + lg * 8;
    const u16* xp = Xl + l15 * LDX + lg * 8;

    f32x4 acc[4][NT];
    #pragma unroll
    for (int mt = 0; mt < 4; ++mt)
        #pragma unroll
        for (int nt = 0; nt < NT; ++nt)
            acc[mt][nt] = (f32x4){0.f, 0.f, 0.f, 0.f};

    short8 a[4], b0[NT], b1[NT];

#define BLOAD(ks, arr) { _Pragma("unroll") \
    for (int nt = 0; nt < NT; ++nt) arr[nt] = *(const short8*)(wp[nt] + (ks) * 32); }
#define ALOAD(ks) { _Pragma("unroll") \
    for (int mt = 0; mt < 4; ++mt) a[mt] = *(const short8*)(xp + mt * 16 * LDX + (ks) * 32); }
#define MFMAS(arr) { _Pragma("unroll") \
    for (int nt = 0; nt < NT; ++nt) { _Pragma("unroll") \
        for (int mt = 0; mt < 4; ++mt) \
            acc[mt][nt] = __builtin_amdgcn_mfma_f32_16x16x32_bf16(a[mt], arr[nt], acc[mt][nt], 0, 0, 0); } }

    BLOAD(0, b0);
    #pragma unroll
    for (int kk = 0; kk < KS / 2; ++kk) {
        BLOAD(2 * kk + 1, b1);
        ALOAD(2 * kk);
        MFMAS(b0);
        if (2 * kk + 2 < KS) BLOAD(2 * kk + 2, b0);
        ALOAD(2 * kk + 1);
        MFMAS(b1);
    }
#undef BLOAD
#undef ALOAD
#undef MFMAS

    // bias + per-n affine params for this lane's columns
    float bv[NT], gv[NT], btv[NT];
    #pragma unroll
    for (int nt = 0; nt < NT; ++nt) {
        int n = nbase + nt * 16 + l15;
        bv[nt] = bias[n]; gv[nt] = gamma[n]; btv[nt] = beta[n];
    }
    #pragma unroll
    for (int mt = 0; mt < 4; ++mt)
        #pragma unroll
        for (int nt = 0; nt < NT; ++nt)
            #pragma unroll
            for (int r = 0; r < 4; ++r)
                acc[mt][nt][r] += bv[nt];

    // per-row partial sum / sumsq over this wave's N/4 columns.
    // C/D layout: col = l15, row = lg*4+r.
    #pragma unroll
    for (int mt = 0; mt < 4; ++mt) {
        float s[4] = {0.f, 0.f, 0.f, 0.f}, q[4] = {0.f, 0.f, 0.f, 0.f};
        #pragma unroll
        for (int nt = 0; nt < NT; ++nt)
            #pragma unroll
            for (int r = 0; r < 4; ++r) {
                float v = acc[mt][nt][r];
                s[r] += v; q[r] += v * v;
            }
        #pragma unroll
        for (int o = 1; o < 16; o <<= 1) {
            #pragma unroll
            for (int r = 0; r < 4; ++r) {
                s[r] += __shfl_xor(s[r], o, 64);
                q[r] += __shfl_xor(q[r], o, 64);
            }
        }
        if (l15 == 0) {
            int row = mt * 16 + lg * 4;
            #pragma unroll
            for (int r = 0; r < 4; ++r) {
                red[(wave * 64 + row + r) * 2 + 0] = s[r];
                red[(wave * 64 + row + r) * 2 + 1] = q[r];
            }
        }
    }
    __syncthreads();
    if (tid < 64) {
        float s = 0.f, q = 0.f;
        #pragma unroll
        for (int w = 0; w < 4; ++w) {
            s += red[(w * 64 + tid) * 2 + 0];
            q += red[(w * 64 + tid) * 2 + 1];
        }
        float mean = s / (float)N;
        float var = q / (float)N - mean * mean;
        stats[tid * 2 + 0] = mean;
        stats[tid * 2 + 1] = rsqrtf(var + 1e-5f);
    }
    __syncthreads();   // also guarantees all X reads done -> Ol/Fl may alias Xl

    #pragma unroll
    for (int mt = 0; mt < 4; ++mt)
        #pragma unroll
        for (int r = 0; r < 4; ++r) {
            int row = mt * 16 + lg * 4 + r;
            float mean = stats[row * 2 + 0];
            float rstd = stats[row * 2 + 1];
            #pragma unroll
            for (int nt = 0; nt < NT; ++nt) {
                float h = (acc[mt][nt][r] - mean) * rstd * gv[nt] + btv[nt];
                if (SILU) h = h / (1.f + __expf(-h));
                int col = nbase + nt * 16 + l15;
                if (FINAL) Fl[row * LDF + col] = h;
                else       Ol[row * LDO + col] = f2bf(h);
            }
        }
    __syncthreads();
}

// ---------------- edge binning: elist[dst*64 + slot] = e (replaces 51M f32 atomics)
__global__ __launch_bounds__(256) void bin_kernel(
    const int* __restrict__ dst_idx, u32* __restrict__ cursor,
    int* __restrict__ elist, int E)
{
    int e = blockIdx.x * 256 + threadIdx.x;
    if (e < E) {
        int d = dst_idx[e];
        u32 slot = atomicAdd(&cursor[d], 1u);
        if (slot < 64u) elist[(size_t)d * 64 + slot] = e;
    }
}

// ---------------- edge kernel: gather+concat -> MLP(384->384->128) -> residual; e_new to ws (bf16)
__global__ __launch_bounds__(256) void edge_kernel(
    const float* __restrict__ e_h, const float* __restrict__ h_src, const float* __restrict__ h_dst,
    const int* __restrict__ src_idx, const int* __restrict__ dst_idx,
    const u16* __restrict__ ew0t, const float* __restrict__ eb0, const float* __restrict__ eg0, const float* __restrict__ ebt0,
    const u16* __restrict__ ew1t, const float* __restrict__ eb1, const float* __restrict__ eg1, const float* __restrict__ ebt1,
    u16* __restrict__ e_new,          // may be null (ws too small) -> dst kernel recomputes from e_out - e_h
    float* __restrict__ e_out, int E)
{
    __shared__ alignas(16) u16 Xbuf[64 * 392];   // 50176 B; reused for H1 (bf16) and F (f32 [64][132])
    __shared__ float red[4 * 64 * 2];
    __shared__ float stats[64 * 2];
    const int tid = threadIdx.x;
    const int eBase = blockIdx.x * 64;

    // stage X = [e_h | h_src[s] | h_dst[d]] as bf16
    for (int i = tid; i < 64 * 96; i += 256) {
        int row = i / 96;
        int col = (i % 96) * 4;
        int e = eBase + row;
        float4 v = make_float4(0.f, 0.f, 0.f, 0.f);
        if (e < E) {
            const float* p;
            if (col < 128)      p = e_h   + (size_t)e * 128 + col;
            else if (col < 256) p = h_src + (size_t)src_idx[e] * 128 + (col - 128);
            else                p = h_dst + (size_t)dst_idx[e] * 128 + (col - 256);
            v = *(const float4*)p;
        }
        ushort4 u;
        u.x = f2bf(v.x); u.y = f2bf(v.y); u.z = f2bf(v.z); u.w = f2bf(v.w);
        *(ushort4*)(Xbuf + row * 392 + col) = u;
    }
    __syncthreads();

    mlp_layer<384, 384, true,  false>(Xbuf, Xbuf, nullptr, red, stats, ew0t, eb0, eg0, ebt0);
    mlp_layer<384, 128, false, true >(Xbuf, nullptr, (float*)Xbuf, red, stats, ew1t, eb1, eg1, ebt1);

    const float* F = (const float*)Xbuf;
    for (int i = tid; i < 64 * 32; i += 256) {
        int row = i >> 5, col = (i & 31) * 4;
        int e = eBase + row;
        if (e < E) {
            float4 v = *(const float4*)(F + row * 132 + col);
            float4 h = *(const float4*)(e_h + (size_t)e * 128 + col);
            float4 o = make_float4(h.x + v.x, h.y + v.y, h.z + v.z, h.w + v.w);
            *(float4*)(e_out + (size_t)e * 128 + col) = o;
            if (e_new) {
                ushort4 u;
                u.x = f2bf(v.x); u.y = f2bf(v.y); u.z = f2bf(v.z); u.w = f2bf(v.w);
                *(ushort4*)(e_new + (size_t)e * 128 + col) = u;
            }
        }
    }
}

// ---------------- dst kernel: [h_dst | gather-sum(e_new)] -> MLP(256->256->128), deg mask, residual
__global__ __launch_bounds__(256) void dst_kernel(
    const float* __restrict__ h_dst,
    const u16* __restrict__ e_new,       // fast path; may be null
    const float* __restrict__ e_out, const float* __restrict__ e_h,   // fallback: e_new = e_out - e_h
    const int* __restrict__ elist, const u32* __restrict__ cursor,
    const u16* __restrict__ dw0t, const float* __restrict__ db0, const float* __restrict__ dg0, const float* __restrict__ dbt0,
    const u16* __restrict__ dw1t, const float* __restrict__ db1, const float* __restrict__ dg1, const float* __restrict__ dbt1,
    float* __restrict__ hd_out, int ND)
{
    __shared__ alignas(16) u16 Xbuf[64 * 264];   // 33792 B; F (f32 [64][132]) aliases exactly
    __shared__ float red[4 * 64 * 2];
    __shared__ float stats[64 * 2];
    const int tid = threadIdx.x;
    const int nBase = blockIdx.x * 64;

    // left half: h_dst -> bf16
    for (int i = tid; i < 64 * 32; i += 256) {
        int row = i >> 5, col = (i & 31) * 4;
        int n = nBase + row;
        float4 v = make_float4(0.f, 0.f, 0.f, 0.f);
        if (n < ND) v = *(const float4*)(h_dst + (size_t)n * 128 + col);
        ushort4 u;
        u.x = f2bf(v.x); u.y = f2bf(v.y); u.z = f2bf(v.z); u.w = f2bf(v.w);
        *(ushort4*)(Xbuf + row * 264 + col) = u;
    }
    // right half: m_sum via per-dst edge-list gather. 4 threads/row, 32 cols each.
    {
        const int r = tid >> 2, q = tid & 3;
        const int n = nBase + r;
        float accm[32];
        #pragma unroll
        for (int c = 0; c < 32; ++c) accm[c] = 0.f;
        if (n < ND) {
            int dg = min((int)cursor[n], 64);
            const int* el = elist + (size_t)n * 64;
            if (e_new) {
                for (int j = 0; j < dg; ++j) {
                    const u16* p = e_new + (size_t)el[j] * 128 + q * 32;
                    #pragma unroll
                    for (int t = 0; t < 4; ++t) {
                        short8 v = *(const short8*)(p + t * 8);
                        #pragma unroll
                        for (int c = 0; c < 8; ++c) accm[t * 8 + c] += bf2f((u16)v[c]);
                    }
                }
            } else {
                for (int j = 0; j < dg; ++j) {
                    const float* po = e_out + (size_t)el[j] * 128 + q * 32;
                    const float* ph = e_h  + (size_t)el[j] * 128 + q * 32;
                    #pragma unroll
                    for (int t = 0; t < 8; ++t) {
                        float4 vo = *(const float4*)(po + t * 4);
                        float4 vh = *(const float4*)(ph + t * 4);
                        accm[t * 4 + 0] += vo.x - vh.x;
                        accm[t * 4 + 1] += vo.y - vh.y;
                        accm[t * 4 + 2] += vo.z - vh.z;
                        accm[t * 4 + 3] += vo.w - vh.w;
                    }
                }
            }
        }
        #pragma unroll
        for (int c4 = 0; c4 < 8; ++c4) {
            ushort4 u;
            u.x = f2bf(accm[c4 * 4 + 0]); u.y = f2bf(accm[c4 * 4 + 1]);
            u.z = f2bf(accm[c4 * 4 + 2]); u.w = f2bf(accm[c4 * 4 + 3]);
            *(ushort4*)(Xbuf + r * 264 + 128 + q * 32 + c4 * 4) = u;
        }
    }
    __syncthreads();

    mlp_layer<256, 256, true,  false>(Xbuf, Xbuf, nullptr, red, stats, dw0t, db0, dg0, dbt0);
    mlp_layer<256, 128, false, true >(Xbuf, nullptr, (float*)Xbuf, red, stats, dw1t, db1, dg1, dbt1);

    const float* F = (const float*)Xbuf;
    for (int i = tid; i < 64 * 32; i += 256) {
        int row = i >> 5, col = (i & 31) * 4;
        int n = nBase + row;
        if (n < ND) {
            bool has = cursor[n] > 0u;
            float4 v = *(const float4*)(F + row * 132 + col);
            float4 h = *(const float4*)(h_dst + (size_t)n * 128 + col);
            float4 o;
            o.x = h.x + (has ? v.x : 0.f);
            o.y = h.y + (has ? v.y : 0.f);
            o.z = h.z + (has ? v.z : 0.f);
            o.w = h.w + (has ? v.w : 0.f);
            *(float4*)(hd_out + (size_t)n * 128 + col) = o;
        }
    }
}

// ---------------- src kernel: h_src -> MLP(128->128->128), residual
__global__ __launch_bounds__(256) void src_kernel(
    const float* __restrict__ h_src,
    const u16* __restrict__ sw0t, const float* __restrict__ sb0, const float* __restrict__ sg0, const float* __restrict__ sbt0,
    const u16* __restrict__ sw1t, const float* __restrict__ sb1, const float* __restrict__ sg1, const float* __restrict__ sbt1,
    float* __restrict__ hs_out, int NS)
{
    __shared__ alignas(16) u16 Xbuf[64 * 264];   // sized for F (f32 [64][132]); layer1 uses [64][136]
    __shared__ float red[4 * 64 * 2];
    __shared__ float stats[64 * 2];
    const int tid = threadIdx.x;
    const int nBase = blockIdx.x * 64;

    for (int i = tid; i < 64 * 32; i += 256) {
        int row = i / 32;
        int col = (i % 32) * 4;
        int n = nBase + row;
        float4 v = make_float4(0.f, 0.f, 0.f, 0.f);
        if (n < NS) v = *(const float4*)(h_src + (size_t)n * 128 + col);
        ushort4 u;
        u.x = f2bf(v.x); u.y = f2bf(v.y); u.z = f2bf(v.z); u.w = f2bf(v.w);
        *(ushort4*)(Xbuf + row * 136 + col) = u;
    }
    __syncthreads();

    mlp_layer<128, 128, true,  false>(Xbuf, Xbuf, nullptr, red, stats, sw0t, sb0, sg0, sbt0);
    mlp_layer<128, 128, false, true >(Xbuf, nullptr, (float*)Xbuf, red, stats, sw1t, sb1, sg1, sbt1);

    const float* F = (const float*)Xbuf;
    for (int i = tid; i < 64 * 32; i += 256) {
        int row = i >> 5, col = (i & 31) * 4;
        int n = nBase + row;
        if (n < NS) {
            float4 v = *(const float4*)(F + row * 132 + col);
            float4 h = *(const float4*)(h_src + (size_t)n * 128 + col);
            float4 o = make_float4(h.x + v.x, h.y + v.y, h.z + v.z, h.w + v.w);
            *(float4*)(hs_out + (size_t)n * 128 + col) = o;
        }
    }
}

// ---------------- weight transpose+cast: W[k][n] f32 -> Wt[n][k] bf16
__global__ __launch_bounds__(256) void wtrans(const float* __restrict__ W, u16* __restrict__ Wt, int K, int N) {
    int i = blockIdx.x * 256 + threadIdx.x;
    if (i < K * N) {
        int k = i / N, n = i % N;
        Wt[(size_t)n * K + k] = f2bf(W[i]);
    }
}

extern "C" void kernel_launch(void* const* d_in, const int* in_sizes, int n_in,
                              void* d_out, int out_size, void* d_ws, size_t ws_size,
                              hipStream_t stream) {
    const float* e_h   = (const float*)d_in[0];
    const float* h_src = (const float*)d_in[1];
    const float* h_dst = (const float*)d_in[2];
    const int* src_idx = (const int*)d_in[3];
    const int* dst_idx = (const int*)d_in[4];
    const float* ew0 = (const float*)d_in[5];
    const float* eb0 = (const float*)d_in[6];
    const float* eg0 = (const float*)d_in[7];
    const float* ebt0 = (const float*)d_in[8];
    const float* ew1 = (const float*)d_in[9];
    const float* eb1 = (const float*)d_in[10];
    const float* eg1 = (const float*)d_in[11];
    const float* ebt1 = (const float*)d_in[12];
    const float* dw0 = (const float*)d_in[13];
    const float* db0 = (const float*)d_in[14];
    const float* dg0 = (const float*)d_in[15];
    const float* dbt0 = (const float*)d_in[16];
    const float* dw1 = (const float*)d_in[17];
    const float* db1 = (const float*)d_in[18];
    const float* dg1 = (const float*)d_in[19];
    const float* dbt1 = (const float*)d_in[20];
    const float* sw0 = (const float*)d_in[21];
    const float* sb0 = (const float*)d_in[22];
    const float* sg0 = (const float*)d_in[23];
    const float* sbt0 = (const float*)d_in[24];
    const float* sw1 = (const float*)d_in[25];
    const float* sb1 = (const float*)d_in[26];
    const float* sg1 = (const float*)d_in[27];
    const float* sbt1 = (const float*)d_in[28];

    const int E  = in_sizes[0] / 128;
    const int NS = in_sizes[1] / 128;
    const int ND = in_sizes[2] / 128;

    // workspace carve-up (all chunks stay 16B-aligned)
    char* ws = (char*)d_ws;
    size_t off = 0;
    int* elist = (int*)(ws + off);  off += (size_t)ND * 64 * 4;
    u32* cursor = (u32*)(ws + off); off += (size_t)ND * 4;
    u16* ew0t = (u16*)(ws + off);   off += (size_t)384 * 384 * 2;
    u16* ew1t = (u16*)(ws + off);   off += (size_t)128 * 384 * 2;
    u16* dw0t = (u16*)(ws + off);   off += (size_t)256 * 256 * 2;
    u16* dw1t = (u16*)(ws + off);   off += (size_t)128 * 256 * 2;
    u16* sw0t = (u16*)(ws + off);   off += (size_t)128 * 128 * 2;
    u16* sw1t = (u16*)(ws + off);   off += (size_t)128 * 128 * 2;
    off = (off + 255) & ~(size_t)255;
    u16* e_new = (u16*)(ws + off);
    size_t need = off + (size_t)E * 128 * 2;
    if (ws_size < need) e_new = nullptr;   // fallback: dst kernel recomputes from e_out - e_h

    hipMemsetAsync(cursor, 0, (size_t)ND * 4, stream);

    wtrans<<<(384 * 384 + 255) / 256, 256, 0, stream>>>(ew0, ew0t, 384, 384);
    wtrans<<<(384 * 128 + 255) / 256, 256, 0, stream>>>(ew1, ew1t, 384, 128);
    wtrans<<<(256 * 256 + 255) / 256, 256, 0, stream>>>(dw0, dw0t, 256, 256);
    wtrans<<<(256 * 128 + 255) / 256, 256, 0, stream>>>(dw1, dw1t, 256, 128);
    wtrans<<<(128 * 128 + 255) / 256, 256, 0, stream>>>(sw0, sw0t, 128, 128);
    wtrans<<<(128 * 128 + 255) / 256, 256, 0, stream>>>(sw1, sw1t, 128, 128);

    bin_kernel<<<(E + 255) / 256, 256, 0, stream>>>(dst_idx, cursor, elist, E);

    float* e_out  = (float*)d_out;
    float* hs_out = e_out + (size_t)E * 128;
    float* hd_out = hs_out + (size_t)NS * 128;

    edge_kernel<<<(E + 63) / 64, 256, 0, stream>>>(
        e_h, h_src, h_dst, src_idx, dst_idx,
        ew0t, eb0, eg0, ebt0, ew1t, eb1, eg1, ebt1,
        e_new, e_out, E);

    src_kernel<<<(NS + 63) / 64, 256, 0, stream>>>(
        h_src, sw0t, sb0, sg0, sbt0, sw1t, sb1, sg1, sbt1, hs_out, NS);

    dst_kernel<<<(ND + 63) / 64, 256, 0, stream>>>(
        h_dst, e_new, e_out, e_h, elist, cursor,
        dw0t, db0, dg0, dbt0, dw1t, db1, dg1, dbt1,
        hd_out, ND);
}

// Round 3
// 776.141 us; speedup vs baseline: 2.1585x; 1.6376x over previous
//
#include <hip/hip_runtime.h>

typedef short short8 __attribute__((ext_vector_type(8)));
typedef float f32x4 __attribute__((ext_vector_type(4)));
typedef unsigned short u16;
typedef unsigned int u32;

__device__ __forceinline__ u16 f2bf(float f) {
    union { float f; u32 u; } v; v.f = f;
    u32 r = (v.u + 0x7FFFu + ((v.u >> 16) & 1u)) >> 16;
    return (u16)r;
}
__device__ __forceinline__ float bf2f(u16 b) {
    union { u32 u; float f; } v; v.u = ((u32)b) << 16; return v.f;
}

// One MLP layer: X (bf16 in LDS, [64][K+8]) @ Wt (bf16 global, [N][K]) + bias,
// row-wise LayerNorm across N, optional SiLU.
// !FINAL: writes bf16 to Ol [64][N+8].  FINAL: writes f32 to Fl [64][N+4].
// Block = NW waves; wave w owns cols [w*N/NW, (w+1)*N/NW).
// B loads double-buffered (b0/b1) so L2 latency hides under the MFMAs.
template<int K, int N, int NW, bool SILU, bool FINAL>
__device__ __forceinline__ void mlp_layer(
    const u16* Xl, u16* Ol, float* Fl,
    float* red, float* stats,
    const u16* __restrict__ Wt, const float* __restrict__ bias,
    const float* __restrict__ gamma, const float* __restrict__ beta)
{
    constexpr int LDX = K + 8;
    constexpr int LDO = N + 8;
    constexpr int LDF = N + 4;
    constexpr int NT = N / (16 * NW);   // 16-col tiles per wave
    constexpr int KS = K / 32;
    static_assert((KS & 1) == 0, "KS must be even");
    static_assert(NT >= 1, "need at least one tile per wave");
    const int tid = threadIdx.x;
    const int wave = tid >> 6;
    const int lane = tid & 63;
    const int l15 = lane & 15;
    const int lg = lane >> 4;
    const int nbase = wave * (N / NW);

    const u16* wp[NT];
    #pragma unroll
    for (int nt = 0; nt < NT; ++nt)
        wp[nt] = Wt + (size_t)(nbase + nt * 16 + l15) * K + lg * 8;
    const u16* xp = Xl + l15 * LDX + lg * 8;

    f32x4 acc[4][NT];
    #pragma unroll
    for (int mt = 0; mt < 4; ++mt)
        #pragma unroll
        for (int nt = 0; nt < NT; ++nt)
            acc[mt][nt] = (f32x4){0.f, 0.f, 0.f, 0.f};

    short8 a[4], b0[NT], b1[NT];

#define BLOAD(ks, arr) { _Pragma("unroll") \
    for (int nt = 0; nt < NT; ++nt) arr[nt] = *(const short8*)(wp[nt] + (ks) * 32); }
#define ALOAD(ks) { _Pragma("unroll") \
    for (int mt = 0; mt < 4; ++mt) a[mt] = *(const short8*)(xp + mt * 16 * LDX + (ks) * 32); }
#define MFMAS(arr) { _Pragma("unroll") \
    for (int nt = 0; nt < NT; ++nt) { _Pragma("unroll") \
        for (int mt = 0; mt < 4; ++mt) \
            acc[mt][nt] = __builtin_amdgcn_mfma_f32_16x16x32_bf16(a[mt], arr[nt], acc[mt][nt], 0, 0, 0); } }

    BLOAD(0, b0);
    #pragma unroll
    for (int kk = 0; kk < KS / 2; ++kk) {
        BLOAD(2 * kk + 1, b1);
        ALOAD(2 * kk);
        MFMAS(b0);
        if (2 * kk + 2 < KS) BLOAD(2 * kk + 2, b0);
        ALOAD(2 * kk + 1);
        MFMAS(b1);
    }
#undef BLOAD
#undef ALOAD
#undef MFMAS

    // bias + per-n affine params for this lane's columns
    float bv[NT], gv[NT], btv[NT];
    #pragma unroll
    for (int nt = 0; nt < NT; ++nt) {
        int n = nbase + nt * 16 + l15;
        bv[nt] = bias[n]; gv[nt] = gamma[n]; btv[nt] = beta[n];
    }
    #pragma unroll
    for (int mt = 0; mt < 4; ++mt)
        #pragma unroll
        for (int nt = 0; nt < NT; ++nt)
            #pragma unroll
            for (int r = 0; r < 4; ++r)
                acc[mt][nt][r] += bv[nt];

    // per-row partial sum / sumsq over this wave's N/NW columns.
    // C/D layout: col = l15, row = lg*4+r.
    #pragma unroll
    for (int mt = 0; mt < 4; ++mt) {
        float s[4] = {0.f, 0.f, 0.f, 0.f}, q[4] = {0.f, 0.f, 0.f, 0.f};
        #pragma unroll
        for (int nt = 0; nt < NT; ++nt)
            #pragma unroll
            for (int r = 0; r < 4; ++r) {
                float v = acc[mt][nt][r];
                s[r] += v; q[r] += v * v;
            }
        #pragma unroll
        for (int o = 1; o < 16; o <<= 1) {
            #pragma unroll
            for (int r = 0; r < 4; ++r) {
                s[r] += __shfl_xor(s[r], o, 64);
                q[r] += __shfl_xor(q[r], o, 64);
            }
        }
        if (l15 == 0) {
            int row = mt * 16 + lg * 4;
            #pragma unroll
            for (int r = 0; r < 4; ++r) {
                red[(wave * 64 + row + r) * 2 + 0] = s[r];
                red[(wave * 64 + row + r) * 2 + 1] = q[r];
            }
        }
    }
    __syncthreads();
    if (tid < 64) {
        float s = 0.f, q = 0.f;
        #pragma unroll
        for (int w = 0; w < NW; ++w) {
            s += red[(w * 64 + tid) * 2 + 0];
            q += red[(w * 64 + tid) * 2 + 1];
        }
        float mean = s / (float)N;
        float var = q / (float)N - mean * mean;
        stats[tid * 2 + 0] = mean;
        stats[tid * 2 + 1] = rsqrtf(var + 1e-5f);
    }
    __syncthreads();   // also guarantees all X reads done -> Ol/Fl may alias Xl

    #pragma unroll
    for (int mt = 0; mt < 4; ++mt)
        #pragma unroll
        for (int r = 0; r < 4; ++r) {
            int row = mt * 16 + lg * 4 + r;
            float mean = stats[row * 2 + 0];
            float rstd = stats[row * 2 + 1];
            #pragma unroll
            for (int nt = 0; nt < NT; ++nt) {
                float h = (acc[mt][nt][r] - mean) * rstd * gv[nt] + btv[nt];
                if (SILU) h = h / (1.f + __expf(-h));
                int col = nbase + nt * 16 + l15;
                if (FINAL) Fl[row * LDF + col] = h;
                else       Ol[row * LDO + col] = f2bf(h);
            }
        }
    __syncthreads();
}

// ---------------- edge binning: elist[dst*64 + slot] = e
__global__ __launch_bounds__(256) void bin_kernel(
    const int* __restrict__ dst_idx, u32* __restrict__ cursor,
    int* __restrict__ elist, int E)
{
    int e = blockIdx.x * 256 + threadIdx.x;
    if (e < E) {
        int d = dst_idx[e];
        u32 slot = atomicAdd(&cursor[d], 1u);
        if (slot < 64u) elist[(size_t)d * 64 + slot] = e;
    }
}

// ---------------- edge kernel: gather+concat -> MLP(384->384->128) -> residual; e_new to ws (bf16)
__global__ __launch_bounds__(512, 4) void edge_kernel(
    const float* __restrict__ e_h, const float* __restrict__ h_src, const float* __restrict__ h_dst,
    const int* __restrict__ src_idx, const int* __restrict__ dst_idx,
    const u16* __restrict__ ew0t, const float* __restrict__ eb0, const float* __restrict__ eg0, const float* __restrict__ ebt0,
    const u16* __restrict__ ew1t, const float* __restrict__ eb1, const float* __restrict__ eg1, const float* __restrict__ ebt1,
    u16* __restrict__ e_new,          // may be null -> dst kernel recomputes from e_out - e_h
    float* __restrict__ e_out, int E)
{
    __shared__ alignas(16) u16 Xbuf[64 * 392];   // 50176 B; reused for H1 (bf16) and F (f32 [64][132])
    __shared__ float red[8 * 64 * 2];
    __shared__ float stats[64 * 2];
    const int tid = threadIdx.x;
    const int eBase = blockIdx.x * 64;

    // stage X = [e_h | h_src[s] | h_dst[d]] as bf16
    for (int i = tid; i < 64 * 96; i += 512) {
        int row = i / 96;
        int col = (i % 96) * 4;
        int e = eBase + row;
        float4 v = make_float4(0.f, 0.f, 0.f, 0.f);
        if (e < E) {
            const float* p;
            if (col < 128)      p = e_h   + (size_t)e * 128 + col;
            else if (col < 256) p = h_src + (size_t)src_idx[e] * 128 + (col - 128);
            else                p = h_dst + (size_t)dst_idx[e] * 128 + (col - 256);
            v = *(const float4*)p;
        }
        ushort4 u;
        u.x = f2bf(v.x); u.y = f2bf(v.y); u.z = f2bf(v.z); u.w = f2bf(v.w);
        *(ushort4*)(Xbuf + row * 392 + col) = u;
    }
    __syncthreads();

    mlp_layer<384, 384, 8, true,  false>(Xbuf, Xbuf, nullptr, red, stats, ew0t, eb0, eg0, ebt0);
    mlp_layer<384, 128, 8, false, true >(Xbuf, nullptr, (float*)Xbuf, red, stats, ew1t, eb1, eg1, ebt1);

    const float* F = (const float*)Xbuf;
    for (int i = tid; i < 64 * 32; i += 512) {
        int row = i >> 5, col = (i & 31) * 4;
        int e = eBase + row;
        if (e < E) {
            float4 v = *(const float4*)(F + row * 132 + col);
            float4 h = *(const float4*)(e_h + (size_t)e * 128 + col);
            float4 o = make_float4(h.x + v.x, h.y + v.y, h.z + v.z, h.w + v.w);
            *(float4*)(e_out + (size_t)e * 128 + col) = o;
            if (e_new) {
                ushort4 u;
                u.x = f2bf(v.x); u.y = f2bf(v.y); u.z = f2bf(v.z); u.w = f2bf(v.w);
                *(ushort4*)(e_new + (size_t)e * 128 + col) = u;
            }
        }
    }
}

// ---------------- dst kernel: [h_dst | gather-sum(e_new)] -> MLP(256->256->128), deg mask, residual
__global__ __launch_bounds__(512, 4) void dst_kernel(
    const float* __restrict__ h_dst,
    const u16* __restrict__ e_new,       // fast path; may be null
    const float* __restrict__ e_out, const float* __restrict__ e_h,   // fallback: e_new = e_out - e_h
    const int* __restrict__ elist, const u32* __restrict__ cursor,
    const u16* __restrict__ dw0t, const float* __restrict__ db0, const float* __restrict__ dg0, const float* __restrict__ dbt0,
    const u16* __restrict__ dw1t, const float* __restrict__ db1, const float* __restrict__ dg1, const float* __restrict__ dbt1,
    float* __restrict__ hd_out, int ND)
{
    __shared__ alignas(16) u16 Xbuf[64 * 264];   // 33792 B; F (f32 [64][132]) aliases exactly
    __shared__ float red[8 * 64 * 2];
    __shared__ float stats[64 * 2];
    const int tid = threadIdx.x;
    const int nBase = blockIdx.x * 64;

    // left half: h_dst -> bf16
    for (int i = tid; i < 64 * 32; i += 512) {
        int row = i >> 5, col = (i & 31) * 4;
        int n = nBase + row;
        float4 v = make_float4(0.f, 0.f, 0.f, 0.f);
        if (n < ND) v = *(const float4*)(h_dst + (size_t)n * 128 + col);
        ushort4 u;
        u.x = f2bf(v.x); u.y = f2bf(v.y); u.z = f2bf(v.z); u.w = f2bf(v.w);
        *(ushort4*)(Xbuf + row * 264 + col) = u;
    }
    // right half: m_sum via per-dst edge-list gather. 8 threads/row, 16 cols each.
    {
        const int r = tid >> 3, q = tid & 7;
        const int n = nBase + r;
        float accm[16];
        #pragma unroll
        for (int c = 0; c < 16; ++c) accm[c] = 0.f;
        if (n < ND) {
            int dg = min((int)cursor[n], 64);
            const int* el = elist + (size_t)n * 64;
            if (e_new) {
                for (int j = 0; j < dg; ++j) {
                    const u16* p = e_new + (size_t)el[j] * 128 + q * 16;
                    #pragma unroll
                    for (int t = 0; t < 2; ++t) {
                        short8 v = *(const short8*)(p + t * 8);
                        #pragma unroll
                        for (int c = 0; c < 8; ++c) accm[t * 8 + c] += bf2f((u16)v[c]);
                    }
                }
            } else {
                for (int j = 0; j < dg; ++j) {
                    const float* po = e_out + (size_t)el[j] * 128 + q * 16;
                    const float* ph = e_h  + (size_t)el[j] * 128 + q * 16;
                    #pragma unroll
                    for (int t = 0; t < 4; ++t) {
                        float4 vo = *(const float4*)(po + t * 4);
                        float4 vh = *(const float4*)(ph + t * 4);
                        accm[t * 4 + 0] += vo.x - vh.x;
                        accm[t * 4 + 1] += vo.y - vh.y;
                        accm[t * 4 + 2] += vo.z - vh.z;
                        accm[t * 4 + 3] += vo.w - vh.w;
                    }
                }
            }
        }
        #pragma unroll
        for (int c4 = 0; c4 < 4; ++c4) {
            ushort4 u;
            u.x = f2bf(accm[c4 * 4 + 0]); u.y = f2bf(accm[c4 * 4 + 1]);
            u.z = f2bf(accm[c4 * 4 + 2]); u.w = f2bf(accm[c4 * 4 + 3]);
            *(ushort4*)(Xbuf + r * 264 + 128 + q * 16 + c4 * 4) = u;
        }
    }
    __syncthreads();

    mlp_layer<256, 256, 8, true,  false>(Xbuf, Xbuf, nullptr, red, stats, dw0t, db0, dg0, dbt0);
    mlp_layer<256, 128, 8, false, true >(Xbuf, nullptr, (float*)Xbuf, red, stats, dw1t, db1, dg1, dbt1);

    const float* F = (const float*)Xbuf;
    for (int i = tid; i < 64 * 32; i += 512) {
        int row = i >> 5, col = (i & 31) * 4;
        int n = nBase + row;
        if (n < ND) {
            bool has = cursor[n] > 0u;
            float4 v = *(const float4*)(F + row * 132 + col);
            float4 h = *(const float4*)(h_dst + (size_t)n * 128 + col);
            float4 o;
            o.x = h.x + (has ? v.x : 0.f);
            o.y = h.y + (has ? v.y : 0.f);
            o.z = h.z + (has ? v.z : 0.f);
            o.w = h.w + (has ? v.w : 0.f);
            *(float4*)(hd_out + (size_t)n * 128 + col) = o;
        }
    }
}

// ---------------- src kernel: h_src -> MLP(128->128->128), residual
__global__ __launch_bounds__(512, 4) void src_kernel(
    const float* __restrict__ h_src,
    const u16* __restrict__ sw0t, const float* __restrict__ sb0, const float* __restrict__ sg0, const float* __restrict__ sbt0,
    const u16* __restrict__ sw1t, const float* __restrict__ sb1, const float* __restrict__ sg1, const float* __restrict__ sbt1,
    float* __restrict__ hs_out, int NS)
{
    __shared__ alignas(16) u16 Xbuf[64 * 264];   // sized for F (f32 [64][132]); layer1 uses [64][136]
    __shared__ float red[8 * 64 * 2];
    __shared__ float stats[64 * 2];
    const int tid = threadIdx.x;
    const int nBase = blockIdx.x * 64;

    for (int i = tid; i < 64 * 32; i += 512) {
        int row = i / 32;
        int col = (i % 32) * 4;
        int n = nBase + row;
        float4 v = make_float4(0.f, 0.f, 0.f, 0.f);
        if (n < NS) v = *(const float4*)(h_src + (size_t)n * 128 + col);
        ushort4 u;
        u.x = f2bf(v.x); u.y = f2bf(v.y); u.z = f2bf(v.z); u.w = f2bf(v.w);
        *(ushort4*)(Xbuf + row * 136 + col) = u;
    }
    __syncthreads();

    mlp_layer<128, 128, 8, true,  false>(Xbuf, Xbuf, nullptr, red, stats, sw0t, sb0, sg0, sbt0);
    mlp_layer<128, 128, 8, false, true >(Xbuf, nullptr, (float*)Xbuf, red, stats, sw1t, sb1, sg1, sbt1);

    const float* F = (const float*)Xbuf;
    for (int i = tid; i < 64 * 32; i += 512) {
        int row = i >> 5, col = (i & 31) * 4;
        int n = nBase + row;
        if (n < NS) {
            float4 v = *(const float4*)(F + row * 132 + col);
            float4 h = *(const float4*)(h_src + (size_t)n * 128 + col);
            float4 o = make_float4(h.x + v.x, h.y + v.y, h.z + v.z, h.w + v.w);
            *(float4*)(hs_out + (size_t)n * 128 + col) = o;
        }
    }
}

// ---------------- weight transpose+cast: W[k][n] f32 -> Wt[n][k] bf16
__global__ __launch_bounds__(256) void wtrans(const float* __restrict__ W, u16* __restrict__ Wt, int K, int N) {
    int i = blockIdx.x * 256 + threadIdx.x;
    if (i < K * N) {
        int k = i / N, n = i % N;
        Wt[(size_t)n * K + k] = f2bf(W[i]);
    }
}

extern "C" void kernel_launch(void* const* d_in, const int* in_sizes, int n_in,
                              void* d_out, int out_size, void* d_ws, size_t ws_size,
                              hipStream_t stream) {
    const float* e_h   = (const float*)d_in[0];
    const float* h_src = (const float*)d_in[1];
    const float* h_dst = (const float*)d_in[2];
    const int* src_idx = (const int*)d_in[3];
    const int* dst_idx = (const int*)d_in[4];
    const float* ew0 = (const float*)d_in[5];
    const float* eb0 = (const float*)d_in[6];
    const float* eg0 = (const float*)d_in[7];
    const float* ebt0 = (const float*)d_in[8];
    const float* ew1 = (const float*)d_in[9];
    const float* eb1 = (const float*)d_in[10];
    const float* eg1 = (const float*)d_in[11];
    const float* ebt1 = (const float*)d_in[12];
    const float* dw0 = (const float*)d_in[13];
    const float* db0 = (const float*)d_in[14];
    const float* dg0 = (const float*)d_in[15];
    const float* dbt0 = (const float*)d_in[16];
    const float* dw1 = (const float*)d_in[17];
    const float* db1 = (const float*)d_in[18];
    const float* dg1 = (const float*)d_in[19];
    const float* dbt1 = (const float*)d_in[20];
    const float* sw0 = (const float*)d_in[21];
    const float* sb0 = (const float*)d_in[22];
    const float* sg0 = (const float*)d_in[23];
    const float* sbt0 = (const float*)d_in[24];
    const float* sw1 = (const float*)d_in[25];
    const float* sb1 = (const float*)d_in[26];
    const float* sg1 = (const float*)d_in[27];
    const float* sbt1 = (const float*)d_in[28];

    const int E  = in_sizes[0] / 128;
    const int NS = in_sizes[1] / 128;
    const int ND = in_sizes[2] / 128;

    // workspace carve-up (all chunks stay 16B-aligned)
    char* ws = (char*)d_ws;
    size_t off = 0;
    int* elist = (int*)(ws + off);  off += (size_t)ND * 64 * 4;
    u32* cursor = (u32*)(ws + off); off += (size_t)ND * 4;
    u16* ew0t = (u16*)(ws + off);   off += (size_t)384 * 384 * 2;
    u16* ew1t = (u16*)(ws + off);   off += (size_t)128 * 384 * 2;
    u16* dw0t = (u16*)(ws + off);   off += (size_t)256 * 256 * 2;
    u16* dw1t = (u16*)(ws + off);   off += (size_t)128 * 256 * 2;
    u16* sw0t = (u16*)(ws + off);   off += (size_t)128 * 128 * 2;
    u16* sw1t = (u16*)(ws + off);   off += (size_t)128 * 128 * 2;
    off = (off + 255) & ~(size_t)255;
    u16* e_new = (u16*)(ws + off);
    size_t need = off + (size_t)E * 128 * 2;
    if (ws_size < need) e_new = nullptr;   // fallback: dst kernel recomputes from e_out - e_h

    hipMemsetAsync(cursor, 0, (size_t)ND * 4, stream);

    wtrans<<<(384 * 384 + 255) / 256, 256, 0, stream>>>(ew0, ew0t, 384, 384);
    wtrans<<<(384 * 128 + 255) / 256, 256, 0, stream>>>(ew1, ew1t, 384, 128);
    wtrans<<<(256 * 256 + 255) / 256, 256, 0, stream>>>(dw0, dw0t, 256, 256);
    wtrans<<<(256 * 128 + 255) / 256, 256, 0, stream>>>(dw1, dw1t, 256, 128);
    wtrans<<<(128 * 128 + 255) / 256, 256, 0, stream>>>(sw0, sw0t, 128, 128);
    wtrans<<<(128 * 128 + 255) / 256, 256, 0, stream>>>(sw1, sw1t, 128, 128);

    bin_kernel<<<(E + 255) / 256, 256, 0, stream>>>(dst_idx, cursor, elist, E);

    float* e_out  = (float*)d_out;
    float* hs_out = e_out + (size_t)E * 128;
    float* hd_out = hs_out + (size_t)NS * 128;

    edge_kernel<<<(E + 63) / 64, 512, 0, stream>>>(
        e_h, h_src, h_dst, src_idx, dst_idx,
        ew0t, eb0, eg0, ebt0, ew1t, eb1, eg1, ebt1,
        e_new, e_out, E);

    src_kernel<<<(NS + 63) / 64, 512, 0, stream>>>(
        h_src, sw0t, sb0, sg0, sbt0, sw1t, sb1, sg1, sbt1, hs_out, NS);

    dst_kernel<<<(ND + 63) / 64, 512, 0, stream>>>(
        h_dst, e_new, e_out, e_h, elist, cursor,
        dw0t, db0, dg0, dbt0, dw1t, db1, dg1, dbt1,
        hd_out, ND);
}

// Round 4
// 729.275 us; speedup vs baseline: 2.2973x; 1.0643x over previous
//
#include <hip/hip_runtime.h>

typedef short short8 __attribute__((ext_vector_type(8)));
typedef float f32x4 __attribute__((ext_vector_type(4)));
typedef unsigned short u16;
typedef unsigned int u32;

__device__ __forceinline__ u16 f2bf(float f) {
    union { float f; u32 u; } v; v.f = f;
    u32 r = (v.u + 0x7FFFu + ((v.u >> 16) & 1u)) >> 16;
    return (u16)r;
}
__device__ __forceinline__ float bf2f(u16 b) {
    union { u32 u; float f; } v; v.u = ((u32)b) << 16; return v.f;
}

// One MLP layer: X (bf16 LDS [64][K+8]) @ Wt (bf16 global [N][K]) + bias,
// row-wise LayerNorm across N, optional SiLU.
// NWA = active waves; wave w (< NWA) owns cols [w*N/NWA, (w+1)*N/NWA).
// Cross-wave LN reduce via LDS float atomicAdd into red_cur[128] (row-major s,q pairs);
// red_next is zeroed for the following layer (ping-pong). 2 barriers per layer.
// !FINAL: writes bf16 to Ol [64][N+8].  FINAL: writes f32 to Fl [64][N+4].
template<int K, int N, int NWA, bool SILU, bool FINAL>
__device__ __forceinline__ void mlp_layer(
    const u16* Xl, u16* Ol, float* Fl,
    float* red_cur, float* red_next,
    const u16* __restrict__ Wt, const float* __restrict__ bias,
    const float* __restrict__ gamma, const float* __restrict__ beta)
{
    constexpr int LDX = K + 8;
    constexpr int LDO = N + 8;
    constexpr int LDF = N + 4;
    constexpr int NT = N / (16 * NWA);   // 16-col tiles per active wave
    constexpr int KS = K / 32;
    static_assert(NT >= 1 && N % (16 * NWA) == 0, "bad split");
    const int tid = threadIdx.x;
    const int wave = tid >> 6;
    const int lane = tid & 63;
    const int l15 = lane & 15;
    const int lg = lane >> 4;

    f32x4 acc[4][NT];

    if (wave < NWA) {
        const int nbase = wave * (N / NWA);
        const u16* wp[NT];
        #pragma unroll
        for (int nt = 0; nt < NT; ++nt)
            wp[nt] = Wt + (size_t)(nbase + nt * 16 + l15) * K + lg * 8;
        const u16* xp = Xl + l15 * LDX + lg * 8;

        #pragma unroll
        for (int mt = 0; mt < 4; ++mt)
            #pragma unroll
            for (int nt = 0; nt < NT; ++nt)
                acc[mt][nt] = (f32x4){0.f, 0.f, 0.f, 0.f};

        short8 a[4], b0[NT], b1[NT];

#define BLOAD(ks, arr) { _Pragma("unroll") \
    for (int nt = 0; nt < NT; ++nt) arr[nt] = *(const short8*)(wp[nt] + (ks) * 32); }
#define ALOAD(ks) { _Pragma("unroll") \
    for (int mt = 0; mt < 4; ++mt) a[mt] = *(const short8*)(xp + mt * 16 * LDX + (ks) * 32); }
#define MFMAS(arr) { _Pragma("unroll") \
    for (int nt = 0; nt < NT; ++nt) { _Pragma("unroll") \
        for (int mt = 0; mt < 4; ++mt) \
            acc[mt][nt] = __builtin_amdgcn_mfma_f32_16x16x32_bf16(a[mt], arr[nt], acc[mt][nt], 0, 0, 0); } }

        BLOAD(0, b0);
        #pragma unroll
        for (int ks = 0; ks < KS; ++ks) {
            if (ks + 1 < KS) {
                if (ks & 1) { BLOAD(ks + 1, b0); } else { BLOAD(ks + 1, b1); }
            }
            ALOAD(ks);
            if (ks & 1) { MFMAS(b1); } else { MFMAS(b0); }
        }
#undef BLOAD
#undef ALOAD
#undef MFMAS

        // bias add
        float bv[NT];
        #pragma unroll
        for (int nt = 0; nt < NT; ++nt) bv[nt] = bias[nbase + nt * 16 + l15];
        #pragma unroll
        for (int mt = 0; mt < 4; ++mt)
            #pragma unroll
            for (int nt = 0; nt < NT; ++nt)
                #pragma unroll
                for (int r = 0; r < 4; ++r)
                    acc[mt][nt][r] += bv[nt];

        // per-row partial (s, q) over this wave's cols; C/D layout: col=l15, row=lg*4+r
        #pragma unroll
        for (int mt = 0; mt < 4; ++mt) {
            float s[4] = {0.f, 0.f, 0.f, 0.f}, q[4] = {0.f, 0.f, 0.f, 0.f};
            #pragma unroll
            for (int nt = 0; nt < NT; ++nt)
                #pragma unroll
                for (int r = 0; r < 4; ++r) {
                    float v = acc[mt][nt][r];
                    s[r] += v; q[r] += v * v;
                }
            #pragma unroll
            for (int o = 1; o < 16; o <<= 1) {
                #pragma unroll
                for (int r = 0; r < 4; ++r) {
                    s[r] += __shfl_xor(s[r], o, 64);
                    q[r] += __shfl_xor(q[r], o, 64);
                }
            }
            if (l15 == 0) {
                int row = mt * 16 + lg * 4;
                #pragma unroll
                for (int r = 0; r < 4; ++r) {
                    atomicAdd(&red_cur[(row + r) * 2 + 0], s[r]);
                    atomicAdd(&red_cur[(row + r) * 2 + 1], q[r]);
                }
            }
        }
    }
    __syncthreads();                       // B1: all partials in red_cur; all X reads done
    if (tid < 128) red_next[tid] = 0.f;    // prep ping-pong buffer for next layer

    if (wave < NWA) {
        const int nbase = wave * (N / NWA);
        float gv[NT], btv[NT];
        #pragma unroll
        for (int nt = 0; nt < NT; ++nt) {
            int n = nbase + nt * 16 + l15;
            gv[nt] = gamma[n]; btv[nt] = beta[n];
        }
        constexpr float invN = 1.f / (float)N;
        #pragma unroll
        for (int mt = 0; mt < 4; ++mt)
            #pragma unroll
            for (int r = 0; r < 4; ++r) {
                int row = mt * 16 + lg * 4 + r;
                float2 sq = *(const float2*)&red_cur[row * 2];
                float mean = sq.x * invN;
                float var = sq.y * invN - mean * mean;
                float rstd = rsqrtf(var + 1e-5f);
                #pragma unroll
                for (int nt = 0; nt < NT; ++nt) {
                    float h = (acc[mt][nt][r] - mean) * rstd * gv[nt] + btv[nt];
                    if (SILU) h = h / (1.f + __expf(-h));
                    int col = nbase + nt * 16 + l15;
                    if (FINAL) Fl[row * LDF + col] = h;
                    else       Ol[row * LDO + col] = f2bf(h);
                }
            }
    }
    __syncthreads();                       // B2: outputs + red_next zeroing visible
}

// ---------------- edge binning: elist[dst*64 + slot] = e
__global__ __launch_bounds__(256) void bin_kernel(
    const int* __restrict__ dst_idx, u32* __restrict__ cursor,
    int* __restrict__ elist, int E)
{
    int e = blockIdx.x * 256 + threadIdx.x;
    if (e < E) {
        int d = dst_idx[e];
        u32 slot = atomicAdd(&cursor[d], 1u);
        if (slot < 64u) elist[(size_t)d * 64 + slot] = e;
    }
}

// ---------------- edge kernel: 768 threads (12 waves), 64 edges/block
__global__ __launch_bounds__(768, 6) void edge_kernel(
    const float* __restrict__ e_h, const float* __restrict__ h_src, const float* __restrict__ h_dst,
    const int* __restrict__ src_idx, const int* __restrict__ dst_idx,
    const u16* __restrict__ ew0t, const float* __restrict__ eb0, const float* __restrict__ eg0, const float* __restrict__ ebt0,
    const u16* __restrict__ ew1t, const float* __restrict__ eb1, const float* __restrict__ eg1, const float* __restrict__ ebt1,
    u16* __restrict__ e_new,          // may be null -> dst kernel recomputes from e_out - e_h
    float* __restrict__ e_out, int E)
{
    __shared__ alignas(16) u16 Xbuf[64 * 392];   // 50176 B; reused: H1 bf16 [64][392], F f32 [64][132]
    __shared__ alignas(8) float red[2][128];
    const int tid = threadIdx.x;
    const int eBase = blockIdx.x * 64;

    if (tid < 256) ((float*)red)[tid] = 0.f;

    // stage X = [e_h | h_src[s] | h_dst[d]] as bf16; 12 threads per row, 8 float4 each
    {
        const int row = tid / 12;
        const int q12 = tid - row * 12;
        if (row < 64) {
            int e = eBase + row;
            u16* xr = Xbuf + row * 392;
            if (e < E) {
                const float* pe = e_h   + (size_t)e * 128;
                const float* ps = h_src + (size_t)src_idx[e] * 128;
                const float* pd = h_dst + (size_t)dst_idx[e] * 128;
                #pragma unroll
                for (int j = 0; j < 8; ++j) {
                    int col = (q12 + j * 12) * 4;           // 0..380
                    const float* p = (col < 128) ? (pe + col)
                                   : (col < 256) ? (ps + col - 128)
                                                 : (pd + col - 256);
                    float4 v = *(const float4*)p;
                    ushort4 u;
                    u.x = f2bf(v.x); u.y = f2bf(v.y); u.z = f2bf(v.z); u.w = f2bf(v.w);
                    *(ushort4*)(xr + col) = u;
                }
            } else {
                #pragma unroll
                for (int j = 0; j < 8; ++j) {
                    int col = (q12 + j * 12) * 4;
                    *(ushort4*)(xr + col) = ushort4{0, 0, 0, 0};
                }
            }
        }
    }
    __syncthreads();

    mlp_layer<384, 384, 12, true,  false>(Xbuf, Xbuf, nullptr, red[0], red[1], ew0t, eb0, eg0, ebt0);
    mlp_layer<384, 128, 8,  false, true >(Xbuf, nullptr, (float*)Xbuf, red[1], red[0], ew1t, eb1, eg1, ebt1);

    const float* F = (const float*)Xbuf;
    for (int i = tid; i < 64 * 32; i += 768) {
        int row = i >> 5, col = (i & 31) * 4;
        int e = eBase + row;
        if (e < E) {
            float4 v = *(const float4*)(F + row * 132 + col);
            float4 h = *(const float4*)(e_h + (size_t)e * 128 + col);
            float4 o = make_float4(h.x + v.x, h.y + v.y, h.z + v.z, h.w + v.w);
            *(float4*)(e_out + (size_t)e * 128 + col) = o;
            if (e_new) {
                ushort4 u;
                u.x = f2bf(v.x); u.y = f2bf(v.y); u.z = f2bf(v.z); u.w = f2bf(v.w);
                *(ushort4*)(e_new + (size_t)e * 128 + col) = u;
            }
        }
    }
}

// ---------------- dst kernel: [h_dst | gather-sum(e_new)] -> MLP(256->256->128), deg mask, residual
__global__ __launch_bounds__(512, 6) void dst_kernel(
    const float* __restrict__ h_dst,
    const u16* __restrict__ e_new,       // fast path; may be null
    const float* __restrict__ e_out, const float* __restrict__ e_h,   // fallback
    const int* __restrict__ elist, const u32* __restrict__ cursor,
    const u16* __restrict__ dw0t, const float* __restrict__ db0, const float* __restrict__ dg0, const float* __restrict__ dbt0,
    const u16* __restrict__ dw1t, const float* __restrict__ db1, const float* __restrict__ dg1, const float* __restrict__ dbt1,
    float* __restrict__ hd_out, int ND)
{
    __shared__ alignas(16) u16 Xbuf[64 * 264];   // 33792 B; F f32 [64][132] aliases
    __shared__ alignas(8) float red[2][128];
    const int tid = threadIdx.x;
    const int nBase = blockIdx.x * 64;

    if (tid < 256) ((float*)red)[tid] = 0.f;

    // left half: h_dst -> bf16 (8 threads/row, 4 float4 each)
    {
        const int row = tid >> 3, q8 = tid & 7;
        int n = nBase + row;
        u16* xr = Xbuf + row * 264;
        #pragma unroll
        for (int j = 0; j < 4; ++j) {
            int col = (q8 + j * 8) * 4;                 // 0..124
            float4 v = make_float4(0.f, 0.f, 0.f, 0.f);
            if (n < ND) v = *(const float4*)(h_dst + (size_t)n * 128 + col);
            ushort4 u;
            u.x = f2bf(v.x); u.y = f2bf(v.y); u.z = f2bf(v.z); u.w = f2bf(v.w);
            *(ushort4*)(xr + col) = u;
        }
    }
    // right half: m_sum via per-dst edge-list gather. 8 threads/row, 16 cols each.
    {
        const int r = tid >> 3, q = tid & 7;
        const int n = nBase + r;
        float accm[16];
        #pragma unroll
        for (int c = 0; c < 16; ++c) accm[c] = 0.f;
        if (n < ND) {
            int dg = min((int)cursor[n], 64);
            const int* el = elist + (size_t)n * 64;
            if (e_new) {
                for (int j = 0; j < dg; ++j) {
                    const u16* p = e_new + (size_t)el[j] * 128 + q * 16;
                    #pragma unroll
                    for (int t = 0; t < 2; ++t) {
                        short8 v = *(const short8*)(p + t * 8);
                        #pragma unroll
                        for (int c = 0; c < 8; ++c) accm[t * 8 + c] += bf2f((u16)v[c]);
                    }
                }
            } else {
                for (int j = 0; j < dg; ++j) {
                    const float* po = e_out + (size_t)el[j] * 128 + q * 16;
                    const float* ph = e_h  + (size_t)el[j] * 128 + q * 16;
                    #pragma unroll
                    for (int t = 0; t < 4; ++t) {
                        float4 vo = *(const float4*)(po + t * 4);
                        float4 vh = *(const float4*)(ph + t * 4);
                        accm[t * 4 + 0] += vo.x - vh.x;
                        accm[t * 4 + 1] += vo.y - vh.y;
                        accm[t * 4 + 2] += vo.z - vh.z;
                        accm[t * 4 + 3] += vo.w - vh.w;
                    }
                }
            }
        }
        #pragma unroll
        for (int c4 = 0; c4 < 4; ++c4) {
            ushort4 u;
            u.x = f2bf(accm[c4 * 4 + 0]); u.y = f2bf(accm[c4 * 4 + 1]);
            u.z = f2bf(accm[c4 * 4 + 2]); u.w = f2bf(accm[c4 * 4 + 3]);
            *(ushort4*)(Xbuf + r * 264 + 128 + q * 16 + c4 * 4) = u;
        }
    }
    __syncthreads();

    mlp_layer<256, 256, 8, true,  false>(Xbuf, Xbuf, nullptr, red[0], red[1], dw0t, db0, dg0, dbt0);
    mlp_layer<256, 128, 8, false, true >(Xbuf, nullptr, (float*)Xbuf, red[1], red[0], dw1t, db1, dg1, dbt1);

    const float* F = (const float*)Xbuf;
    for (int i = tid; i < 64 * 32; i += 512) {
        int row = i >> 5, col = (i & 31) * 4;
        int n = nBase + row;
        if (n < ND) {
            bool has = cursor[n] > 0u;
            float4 v = *(const float4*)(F + row * 132 + col);
            float4 h = *(const float4*)(h_dst + (size_t)n * 128 + col);
            float4 o;
            o.x = h.x + (has ? v.x : 0.f);
            o.y = h.y + (has ? v.y : 0.f);
            o.z = h.z + (has ? v.z : 0.f);
            o.w = h.w + (has ? v.w : 0.f);
            *(float4*)(hd_out + (size_t)n * 128 + col) = o;
        }
    }
}

// ---------------- src kernel: h_src -> MLP(128->128->128), residual
__global__ __launch_bounds__(512, 6) void src_kernel(
    const float* __restrict__ h_src,
    const u16* __restrict__ sw0t, const float* __restrict__ sb0, const float* __restrict__ sg0, const float* __restrict__ sbt0,
    const u16* __restrict__ sw1t, const float* __restrict__ sb1, const float* __restrict__ sg1, const float* __restrict__ sbt1,
    float* __restrict__ hs_out, int NS)
{
    __shared__ alignas(16) u16 Xbuf[64 * 264];
    __shared__ alignas(8) float red[2][128];
    const int tid = threadIdx.x;
    const int nBase = blockIdx.x * 64;

    if (tid < 256) ((float*)red)[tid] = 0.f;

    {
        const int row = tid >> 3, q8 = tid & 7;
        int n = nBase + row;
        u16* xr = Xbuf + row * 136;
        #pragma unroll
        for (int j = 0; j < 4; ++j) {
            int col = (q8 + j * 8) * 4;
            float4 v = make_float4(0.f, 0.f, 0.f, 0.f);
            if (n < NS) v = *(const float4*)(h_src + (size_t)n * 128 + col);
            ushort4 u;
            u.x = f2bf(v.x); u.y = f2bf(v.y); u.z = f2bf(v.z); u.w = f2bf(v.w);
            *(ushort4*)(xr + col) = u;
        }
    }
    __syncthreads();

    mlp_layer<128, 128, 8, true,  false>(Xbuf, Xbuf, nullptr, red[0], red[1], sw0t, sb0, sg0, sbt0);
    mlp_layer<128, 128, 8, false, true >(Xbuf, nullptr, (float*)Xbuf, red[1], red[0], sw1t, sb1, sg1, sbt1);

    const float* F = (const float*)Xbuf;
    for (int i = tid; i < 64 * 32; i += 512) {
        int row = i >> 5, col = (i & 31) * 4;
        int n = nBase + row;
        if (n < NS) {
            float4 v = *(const float4*)(F + row * 132 + col);
            float4 h = *(const float4*)(h_src + (size_t)n * 128 + col);
            float4 o = make_float4(h.x + v.x, h.y + v.y, h.z + v.z, h.w + v.w);
            *(float4*)(hs_out + (size_t)n * 128 + col) = o;
        }
    }
}

// ---------------- weight transpose+cast: W[k][n] f32 -> Wt[n][k] bf16
__global__ __launch_bounds__(256) void wtrans(const float* __restrict__ W, u16* __restrict__ Wt, int K, int N) {
    int i = blockIdx.x * 256 + threadIdx.x;
    if (i < K * N) {
        int k = i / N, n = i % N;
        Wt[(size_t)n * K + k] = f2bf(W[i]);
    }
}

extern "C" void kernel_launch(void* const* d_in, const int* in_sizes, int n_in,
                              void* d_out, int out_size, void* d_ws, size_t ws_size,
                              hipStream_t stream) {
    const float* e_h   = (const float*)d_in[0];
    const float* h_src = (const float*)d_in[1];
    const float* h_dst = (const float*)d_in[2];
    const int* src_idx = (const int*)d_in[3];
    const int* dst_idx = (const int*)d_in[4];
    const float* ew0 = (const float*)d_in[5];
    const float* eb0 = (const float*)d_in[6];
    const float* eg0 = (const float*)d_in[7];
    const float* ebt0 = (const float*)d_in[8];
    const float* ew1 = (const float*)d_in[9];
    const float* eb1 = (const float*)d_in[10];
    const float* eg1 = (const float*)d_in[11];
    const float* ebt1 = (const float*)d_in[12];
    const float* dw0 = (const float*)d_in[13];
    const float* db0 = (const float*)d_in[14];
    const float* dg0 = (const float*)d_in[15];
    const float* dbt0 = (const float*)d_in[16];
    const float* dw1 = (const float*)d_in[17];
    const float* db1 = (const float*)d_in[18];
    const float* dg1 = (const float*)d_in[19];
    const float* dbt1 = (const float*)d_in[20];
    const float* sw0 = (const float*)d_in[21];
    const float* sb0 = (const float*)d_in[22];
    const float* sg0 = (const float*)d_in[23];
    const float* sbt0 = (const float*)d_in[24];
    const float* sw1 = (const float*)d_in[25];
    const float* sb1 = (const float*)d_in[26];
    const float* sg1 = (const float*)d_in[27];
    const float* sbt1 = (const float*)d_in[28];

    const int E  = in_sizes[0] / 128;
    const int NS = in_sizes[1] / 128;
    const int ND = in_sizes[2] / 128;

    // workspace carve-up (16B-aligned chunks)
    char* ws = (char*)d_ws;
    size_t off = 0;
    int* elist = (int*)(ws + off);  off += (size_t)ND * 64 * 4;
    u32* cursor = (u32*)(ws + off); off += (size_t)ND * 4;
    u16* ew0t = (u16*)(ws + off);   off += (size_t)384 * 384 * 2;
    u16* ew1t = (u16*)(ws + off);   off += (size_t)128 * 384 * 2;
    u16* dw0t = (u16*)(ws + off);   off += (size_t)256 * 256 * 2;
    u16* dw1t = (u16*)(ws + off);   off += (size_t)128 * 256 * 2;
    u16* sw0t = (u16*)(ws + off);   off += (size_t)128 * 128 * 2;
    u16* sw1t = (u16*)(ws + off);   off += (size_t)128 * 128 * 2;
    off = (off + 255) & ~(size_t)255;
    u16* e_new = (u16*)(ws + off);
    size_t need = off + (size_t)E * 128 * 2;
    if (ws_size < need) e_new = nullptr;   // fallback: dst kernel recomputes from e_out - e_h

    hipMemsetAsync(cursor, 0, (size_t)ND * 4, stream);

    wtrans<<<(384 * 384 + 255) / 256, 256, 0, stream>>>(ew0, ew0t, 384, 384);
    wtrans<<<(384 * 128 + 255) / 256, 256, 0, stream>>>(ew1, ew1t, 384, 128);
    wtrans<<<(256 * 256 + 255) / 256, 256, 0, stream>>>(dw0, dw0t, 256, 256);
    wtrans<<<(256 * 128 + 255) / 256, 256, 0, stream>>>(dw1, dw1t, 256, 128);
    wtrans<<<(128 * 128 + 255) / 256, 256, 0, stream>>>(sw0, sw0t, 128, 128);
    wtrans<<<(128 * 128 + 255) / 256, 256, 0, stream>>>(sw1, sw1t, 128, 128);

    bin_kernel<<<(E + 255) / 256, 256, 0, stream>>>(dst_idx, cursor, elist, E);

    float* e_out  = (float*)d_out;
    float* hs_out = e_out + (size_t)E * 128;
    float* hd_out = hs_out + (size_t)NS * 128;

    edge_kernel<<<(E + 63) / 64, 768, 0, stream>>>(
        e_h, h_src, h_dst, src_idx, dst_idx,
        ew0t, eb0, eg0, ebt0, ew1t, eb1, eg1, ebt1,
        e_new, e_out, E);

    src_kernel<<<(NS + 63) / 64, 512, 0, stream>>>(
        h_src, sw0t, sb0, sg0, sbt0, sw1t, sb1, sg1, sbt1, hs_out, NS);

    dst_kernel<<<(ND + 63) / 64, 512, 0, stream>>>(
        h_dst, e_new, e_out, e_h, elist, cursor,
        dw0t, db0, dg0, dbt0, dw1t, db1, dg1, dbt1,
        hd_out, ND);
}